// Round 5
// baseline (136.816 us; speedup 1.0000x reference)
//
#include <hip/hip_runtime.h>

// Problem constants
#define N_PTS   65536      // B*H*W = 64*32*32
#define K_CODES 1024
#define C_DIM   64
#define HW      1024
#define Q_ELEMS 4194304

// d_out layout (float32): [vq_loss(1) | quantized(4194304) | perplexity(1) | indices(65536)]
#define OUT_Q_OFF 1
#define OUT_P_OFF 4194305
#define OUT_I_OFF 4194306

// ws layout (bytes)
#define WS_HIST 0          // 1024 u32    (4096)
#define WS_SSE  4096       // 1 double    (8)
#define WS_CSUM 8192       // 1024 f32    (4096)
#define WS_CBP  16384      // packed A-frags: 32 tiles * 8 slots * 512 shorts = 262144 B

// Screen metric is w = x.c - csum/2 (argmin dist == argmax w). Proven dist-space
// thresholds EPS_A=1.5e-4 / EPS_T=4e-4 map to w-space /2:
#define EPS_A_W 7.5e-5f    // ambiguous if m2 >= m1 - EPS_A_W
#define EPS_T_W 2.0e-4f    // candidate tile if tmax >= m1 - EPS_T_W

typedef float f32x16 __attribute__((ext_vector_type(16)));
typedef short bf16x8 __attribute__((ext_vector_type(8)));

__device__ __forceinline__ unsigned short bf16rn(float f) {
    unsigned int u = __float_as_uint(f);
    return (unsigned short)((u + 0x7FFFu + ((u >> 16) & 1u)) >> 16);
}
__device__ __forceinline__ float bf16tof(unsigned short h) {
    return __uint_as_float(((unsigned int)h) << 16);
}

// async global->LDS, 16B per lane, wave-uniform LDS base (lane*16 added by HW)
__device__ __forceinline__ void gload_lds16(const void* g, void* l) {
    __builtin_amdgcn_global_load_lds(
        (const __attribute__((address_space(1))) unsigned int*)g,
        (__attribute__((address_space(3))) unsigned int*)l, 16, 0, 0);
}

// numpy pairwise sum (n=64): 8 accumulators striding 8, then pairwise combine.
__device__ __forceinline__ float np_pairwise_sumsq64(const float* a) {
    float r[8];
    #pragma unroll
    for (int j = 0; j < 8; ++j) r[j] = __fmul_rn(a[j], a[j]);
    #pragma unroll
    for (int i = 8; i < 64; i += 8) {
        #pragma unroll
        for (int j = 0; j < 8; ++j)
            r[j] = __fadd_rn(r[j], __fmul_rn(a[i + j], a[i + j]));
    }
    return __fadd_rn(__fadd_rn(__fadd_rn(r[0], r[1]), __fadd_rn(r[2], r[3])),
                     __fadd_rn(__fadd_rn(r[4], r[5]), __fadd_rn(r[6], r[7])));
}

// Prep (2048 threads): csum + codebook packed into MFMA A-frag order.
// No bias slot anymore (csum is applied as the f32 C-init of the first MFMA
// in vq_main) -> tile = 8 slots * 512 shorts = 8KB exactly.
// Also zeroes hist/sse (kernel boundary publishes before vq_main).
__global__ void vq_prep(const float* __restrict__ cb, float* __restrict__ csum,
                        unsigned short* __restrict__ cbp,
                        unsigned int* __restrict__ hist,
                        double* __restrict__ sse) {
    int g = blockIdx.x * 256 + threadIdx.x;   // 0..2047
    if (g < 1024) hist[g] = 0u;
    if (g == 1024) *sse = 0.0;
    int t = g >> 6, lane = g & 63, l31 = lane & 31, half = lane >> 5;
    int row = t * 32 + l31;
    const float* r = cb + row * 64;
    float cs = np_pairwise_sumsq64(r);
    if (half == 0) csum[row] = cs;
    size_t tb = (size_t)t * 4096;             // shorts per tile (8 slots * 512)
    #pragma unroll
    for (int c = 0; c < 4; ++c) {
        bf16x8 h8, l8;
        #pragma unroll
        for (int j = 0; j < 8; ++j) {
            float f = r[c * 16 + half * 8 + j];
            unsigned short h = bf16rn(f);
            h8[j] = (short)h;
            l8[j] = (short)bf16rn(f - bf16tof(h));
        }
        *(bf16x8*)(cbp + tb + (size_t)(c * 2 + 0) * 512 + lane * 8) = h8;
        *(bf16x8*)(cbp + tb + (size_t)(c * 2 + 1) * 512 + lane * 8) = l8;
    }
}

// Main: block = 128 points, 4 waves; each wave screens its own 32 points
// against all 32 tiles. R0/R4 A/B proved waves/CU is NOT the limiter: both
// moved ~2.3MB/CU of codebook through the ~64B/cyc L1/vmem port (per-wave
// redundant streaming) and both hit ~72us. Fix: stage each tile through LDS
// ONCE per block (global_load_lds, 16B/lane, linear dest = m97 pattern),
// double-buffered in 2x4KB half-tile buffers -> per-CU codebook traffic
// drops 2.3MB -> 512KB; reuse served by the 128B/cyc LDS pipe.
// Sync: plain __syncthreads() per half-step. Its mandatory vmcnt(0)+lgkmcnt(0)
// drain is exactly the needed wait: prefetch issued mid-step is drained at the
// next barrier; each wave's ds_reads are drained before any wave can overwrite
// that buffer. Race-free with zero inline asm.
// csum enters as the exact-f32 C-operand of the first MFMA (was a bf16-rounded
// K=65 bias row): one less MFMA/tile, exact bias, staging halves exactly 4KB.
// Two accumulators (one per half) shorten MFMA dep chains 12 -> 6.
// launch_bounds (256,1): measured gfx950 cap law arch-VGPR = 256/min_waves;
// min_waves=1 -> no cap -> no spill risk ((256,4)/(512,4) capped to 64 and
// spilled catastrophically in R1/R2). Grid 512 = 2 blocks/CU; LDS 63.5KB x2
// = 127KB < 160KB.
__global__ __launch_bounds__(256, 1) void vq_main(
        const float* __restrict__ latents,
        const float* __restrict__ cb,
        const float* __restrict__ csum,
        const unsigned short* __restrict__ cbp,
        unsigned int* __restrict__ hist,
        double* __restrict__ sse,
        float* __restrict__ out) {
    __shared__ float xs[128 * 65];            // 33.3 KB, stride 65 (x, then q)
    __shared__ float tmax[32 * 128];          // 16 KB per-(tile,point) screen max
    __shared__ float csl[1024];               // 4 KB: -csum/2 (f32, exact)
    __shared__ __align__(16) short stg[2][2048];  // 8 KB: double-buffered half-tiles
    __shared__ float m1f[128];
    __shared__ int   fk[128], ambig[128], acount;
    __shared__ double wred[4];

    const int tid  = threadIdx.x;
    const int lane = tid & 63, wave = tid >> 6;   // wave 0..3
    const int n0 = blockIdx.x * 128;
    const int b = n0 >> 10, hw0 = n0 & 1023;
    const float* xg = latents + (size_t)b * C_DIM * HW + hw0;

    for (int i = tid; i < 128 * 64; i += 256) {
        int p = i & 127, d = i >> 7;
        xs[p * 65 + d] = xg[(size_t)d * HW + p];
    }
    for (int i = tid; i < 1024; i += 256) csl[i] = -0.5f * csum[i];
    if (tid == 0) acount = 0;
    __syncthreads();

    // B-frags: col = lane&31 -> point, k = (lane>>5)*8 + j
    const int l31 = lane & 31, half = lane >> 5;
    const int pb = (wave << 5) + l31;
    bf16x8 xh[4], xl[4];
    #pragma unroll
    for (int c = 0; c < 4; ++c)
        #pragma unroll
        for (int j = 0; j < 8; ++j) {
            float f = xs[pb * 65 + c * 16 + half * 8 + j];
            unsigned short h = bf16rn(f);
            xh[c][j] = (short)h;
            xl[c][j] = (short)bf16rn(f - bf16tof(h));
        }

    f32x16 zacc;
    #pragma unroll
    for (int r = 0; r < 16; ++r) zacc[r] = 0.0f;

    float m1 = -3e38f, m2 = -3e38f;
    int i1 = 0;
    const int RC[16] = {0,1,2,3,8,9,10,11,16,17,18,19,24,25,26,27};
    const int rh4 = half * 4;
    const char* cbpB = (const char*)cbp;      // step s covers bytes [s*4096, +4096)
    char* lds0 = (char*)&stg[0][0] + wave * 1024;
    char* lds1 = (char*)&stg[1][0] + wave * 1024;

    // prologue: stage step 0 (tile 0, half A) into buf0
    gload_lds16(cbpB + (size_t)tid * 16, lds0);

    for (int t = 0; t < 32; ++t) {
        // ---- step 2t (half A: chunks 0,1) ----
        __syncthreads();                      // drains buf0 load + prior ds_reads
        const bf16x8* s0 = (const bf16x8*)&stg[0][0];
        bf16x8 a0 = s0[lane], a1 = s0[64 + lane], a2 = s0[128 + lane], a3 = s0[192 + lane];
        f32x16 csv;
        {
            const int cb0 = (t << 5) + rh4;
            #pragma unroll
            for (int q = 0; q < 4; ++q) {
                float4 c4 = *(const float4*)&csl[cb0 + q * 8];
                csv[q * 4 + 0] = c4.x; csv[q * 4 + 1] = c4.y;
                csv[q * 4 + 2] = c4.z; csv[q * 4 + 3] = c4.w;
            }
        }
        // prefetch half B of tile t (drained at next barrier)
        gload_lds16(cbpB + ((size_t)(2 * t + 1)) * 4096 + (size_t)tid * 16, lds1);
        f32x16 acc0 = __builtin_amdgcn_mfma_f32_32x32x16_bf16(a0, xh[0], csv, 0, 0, 0);
        acc0 = __builtin_amdgcn_mfma_f32_32x32x16_bf16(a0, xl[0], acc0, 0, 0, 0);
        acc0 = __builtin_amdgcn_mfma_f32_32x32x16_bf16(a1, xh[0], acc0, 0, 0, 0);
        acc0 = __builtin_amdgcn_mfma_f32_32x32x16_bf16(a2, xh[1], acc0, 0, 0, 0);
        acc0 = __builtin_amdgcn_mfma_f32_32x32x16_bf16(a2, xl[1], acc0, 0, 0, 0);
        acc0 = __builtin_amdgcn_mfma_f32_32x32x16_bf16(a3, xh[1], acc0, 0, 0, 0);

        // ---- step 2t+1 (half B: chunks 2,3) ----
        __syncthreads();                      // drains buf1 load + buf0 ds_reads
        const bf16x8* s1 = (const bf16x8*)&stg[1][0];
        bf16x8 b0 = s1[lane], b1 = s1[64 + lane], b2 = s1[128 + lane], b3 = s1[192 + lane];
        if (t < 31)                           // prefetch half A of tile t+1
            gload_lds16(cbpB + ((size_t)(2 * t + 2)) * 4096 + (size_t)tid * 16, lds0);
        f32x16 acc1 = __builtin_amdgcn_mfma_f32_32x32x16_bf16(b0, xh[2], zacc, 0, 0, 0);
        acc1 = __builtin_amdgcn_mfma_f32_32x32x16_bf16(b0, xl[2], acc1, 0, 0, 0);
        acc1 = __builtin_amdgcn_mfma_f32_32x32x16_bf16(b1, xh[2], acc1, 0, 0, 0);
        acc1 = __builtin_amdgcn_mfma_f32_32x32x16_bf16(b2, xh[3], acc1, 0, 0, 0);
        acc1 = __builtin_amdgcn_mfma_f32_32x32x16_bf16(b2, xl[3], acc1, 0, 0, 0);
        acc1 = __builtin_amdgcn_mfma_f32_32x32x16_bf16(b3, xh[3], acc1, 0, 0, 0);

        // within-tile top-2 + first-argmax (5 VALU/value incl. the half-combine)
        float vl = -3e38f, sl = -3e38f;
        int kl = 0;
        #pragma unroll
        for (int r = 0; r < 16; ++r) {
            float v = acc0[r] + acc1[r];
            sl = __builtin_amdgcn_fmed3f(v, sl, vl);   // = max(sl, min(vl_old, v))
            bool c2 = v > vl;                           // strict >: first-max
            kl = c2 ? RC[r] : kl;
            vl = fmaxf(vl, v);
        }
        int k = (t << 5) + rh4 + kl;
        bool cg = vl > m1;                              // strict: earlier tile wins ties
        i1 = cg ? k : i1;
        float X = cg ? sl : m2;
        m2 = __builtin_amdgcn_fmed3f(vl, X, m1);        // = max(min(m1,vl), X)
        m1 = fmaxf(m1, vl);
        float tlm = fmaxf(vl, __shfl_xor(vl, 32, 64));
        if (half == 0) tmax[t * 128 + pb] = tlm;
    }

    // cross-half merge; ties resolve via ambiguous path
    {
        float m1o = __shfl_xor(m1, 32, 64);
        float m2o = __shfl_xor(m2, 32, 64);
        int   i1o = __shfl_xor(i1, 32, 64);
        m2 = fmaxf(fmaxf(m2, m2o), fminf(m1, m1o));
        i1 = (m1o > m1) ? i1o : i1;
        m1 = fmaxf(m1, m1o);
        if (half == 0) {
            m1f[pb] = m1;
            fk[pb] = i1;
            if (m2 >= m1 - EPS_A_W) {
                int a = atomicAdd(&acount, 1);
                ambig[a] = pb;
            }
        }
    }
    __syncthreads();

    // Exact rescan: one wave per ambiguous point, candidate tiles only.
    // Reference-bit-exact: dist = fl32(fl32(A+csum[k]) - fl32(2*seqFMA)).
    for (int a = wave; a < acount; a += 4) {
        int p = ambig[a];
        const float* xrow = &xs[p * 65];
        float Aq = np_pairwise_sumsq64(xrow);
        float thr = m1f[p] - EPS_T_W;
        unsigned long long best = ~0ULL;
        for (int t = 0; t < 32; ++t) {
            if (tmax[t * 128 + p] < thr) continue;   // wave-uniform branch
            if (lane < 32) {
                int k = (t << 5) + lane;
                const float* crow = cb + (size_t)k * 64;
                float m = 0.0f;
                #pragma unroll
                for (int d = 0; d < 64; ++d) m = __fmaf_rn(xrow[d], crow[d], m);
                float D = __fsub_rn(__fadd_rn(Aq, csum[k]), __fmul_rn(2.0f, m));
                unsigned long long key =
                    ((unsigned long long)__float_as_uint(D) << 10) | (unsigned)k;
                best = (key < best) ? key : best;
            }
        }
        #pragma unroll
        for (int off = 32; off > 0; off >>= 1) {
            unsigned long long o = __shfl_xor(best, off, 64);
            best = (o < best) ? o : best;
        }
        if (lane == 0) fk[p] = (int)(best & 1023ULL);
    }
    __syncthreads();

    // indices + histogram
    if (tid < 128) {
        int myk = fk[tid];
        out[OUT_I_OFF + n0 + tid] = (float)myk;
        atomicAdd(&hist[myk], 1u);
    }
    // Fused stage+SSE: read each selected cb row ONCE row-coalesced (float4),
    // accumulate f64 SSE against x in xs, overwrite xs with q for write-out.
    double e = 0.0;
    #pragma unroll
    for (int i2 = 0; i2 < 8; ++i2) {
        int i = tid + i2 * 256;               // 0..2047
        int p = i >> 4, seg = i & 15;
        const float4 q = *(const float4*)(cb + (size_t)fk[p] * 64 + seg * 4);
        float* xp = &xs[p * 65 + seg * 4];    // stride-65: only 4B aligned -> scalar ops
        float x0 = xp[0], x1 = xp[1], x2 = xp[2], x3 = xp[3];
        double d0 = (double)x0 - (double)q.x; e = fma(d0, d0, e);
        double d1 = (double)x1 - (double)q.y; e = fma(d1, d1, e);
        double d2 = (double)x2 - (double)q.z; e = fma(d2, d2, e);
        double d3 = (double)x3 - (double)q.w; e = fma(d3, d3, e);
        xp[0] = q.x; xp[1] = q.y; xp[2] = q.z; xp[3] = q.w;
    }
    #pragma unroll
    for (int off = 32; off > 0; off >>= 1) e += __shfl_down(e, off, 64);
    if (lane == 0) wred[wave] = e;
    __syncthreads();
    if (tid == 0) {
        double s = 0.0;
        #pragma unroll
        for (int w = 0; w < 4; ++w) s += wred[w];
        atomicAdd(sse, s);
    }
    // quantized [B,C,H,W]: coalesced 128-float store rows per c, from staged xs
    for (int i = tid; i < 128 * 64; i += 256) {
        int p = i & 127, c = i >> 7;
        out[OUT_Q_OFF + (size_t)b * 65536 + (size_t)c * HW + hw0 + p] = xs[p * 65 + c];
    }
}

// Finalize: perplexity from histogram, vq_loss from SSE. Separate launch —
// the kernel boundary provides device-wide visibility of hist/sse without
// any per-block L2-writeback fence.
__global__ void vq_final(const unsigned int* __restrict__ hist,
                         const double* __restrict__ sse,
                         float* __restrict__ out) {
    __shared__ double red[256];
    int t = threadIdx.x;
    double s = 0.0;
    for (int i = t; i < K_CODES; i += 256) {
        double p = (double)hist[i] / (double)N_PTS;
        s += p * log(p + 1e-10);
    }
    red[t] = s;
    __syncthreads();
    for (int w = 128; w > 0; w >>= 1) {
        if (t < w) red[t] += red[t + w];
        __syncthreads();
    }
    if (t == 0) {
        out[OUT_P_OFF] = (float)exp(-red[0]);
        out[0] = (float)(1.25 * sse[0] / (double)Q_ELEMS);
    }
}

extern "C" void kernel_launch(void* const* d_in, const int* in_sizes, int n_in,
                              void* d_out, int out_size, void* d_ws, size_t ws_size,
                              hipStream_t stream) {
    const float* latents = (const float*)d_in[0];
    const float* cb      = (const float*)d_in[1];
    float* out = (float*)d_out;
    char* ws = (char*)d_ws;

    unsigned int*   hist = (unsigned int*)(ws + WS_HIST);
    double*         sse  = (double*)(ws + WS_SSE);
    float*          csum = (float*)(ws + WS_CSUM);
    unsigned short* cbp  = (unsigned short*)(ws + WS_CBP);

    vq_prep <<<8, 256, 0, stream>>>(cb, csum, cbp, hist, sse);
    vq_main <<<N_PTS / 128, 256, 0, stream>>>(latents, cb, csum, cbp,
                                              hist, sse, out);
    vq_final<<<1, 256, 0, stream>>>(hist, sse, out);
}

// Round 9
// 133.804 us; speedup vs baseline: 1.0225x; 1.0225x over previous
//
#include <hip/hip_runtime.h>

// Problem constants
#define N_PTS   65536      // B*H*W = 64*32*32
#define K_CODES 1024
#define C_DIM   64
#define HW      1024
#define Q_ELEMS 4194304

// d_out layout (float32): [vq_loss(1) | quantized(4194304) | perplexity(1) | indices(65536)]
#define OUT_Q_OFF 1
#define OUT_P_OFF 4194305
#define OUT_I_OFF 4194306

// ws layout (bytes)
#define WS_HIST 0          // 1024 u32    (4096)
#define WS_SSE  4096       // 1 double    (8)
#define WS_DONE 4104       // 1 u32       (4)
#define WS_CSUM 8192       // 1024 f32    (4096)
#define WS_CBP  16384      // packed A-frags: 32 tiles * 8 slots * 512 shorts = 262144 B

// Screen metric is w = x.c - csum/2 (argmin dist == argmax w). Proven dist-space
// thresholds EPS_A=1.5e-4 / EPS_T=4e-4 map to w-space /2. (R6/R7's hi-only
// screen + adaptive bound failed twice on indices with unchanged absmax across
// a 2x bound widening -> structural, reverted to this R0-R5-validated form.)
#define EPS_A_W 7.5e-5f    // ambiguous if m2 >= m1 - EPS_A_W
#define EPS_T_W 2.0e-4f    // candidate tile if tmax >= m1 - EPS_T_W

typedef float f32x16 __attribute__((ext_vector_type(16)));
typedef short bf16x8 __attribute__((ext_vector_type(8)));

__device__ __forceinline__ unsigned short bf16rn(float f) {
    unsigned int u = __float_as_uint(f);
    return (unsigned short)((u + 0x7FFFu + ((u >> 16) & 1u)) >> 16);
}
__device__ __forceinline__ float bf16tof(unsigned short h) {
    return __uint_as_float(((unsigned int)h) << 16);
}

// async global->LDS, 16B per lane, wave-uniform LDS base (lane*16 added by HW)
__device__ __forceinline__ void gload_lds16(const void* g, void* l) {
    __builtin_amdgcn_global_load_lds(
        (const __attribute__((address_space(1))) unsigned int*)g,
        (__attribute__((address_space(3))) unsigned int*)l, 16, 0, 0);
}

// numpy pairwise sum (n=64): 8 accumulators striding 8, then pairwise combine.
__device__ __forceinline__ float np_pairwise_sumsq64(const float* a) {
    float r[8];
    #pragma unroll
    for (int j = 0; j < 8; ++j) r[j] = __fmul_rn(a[j], a[j]);
    #pragma unroll
    for (int i = 8; i < 64; i += 8) {
        #pragma unroll
        for (int j = 0; j < 8; ++j)
            r[j] = __fadd_rn(r[j], __fmul_rn(a[i + j], a[i + j]));
    }
    return __fadd_rn(__fadd_rn(__fadd_rn(r[0], r[1]), __fadd_rn(r[2], r[3])),
                     __fadd_rn(__fadd_rn(r[4], r[5]), __fadd_rn(r[6], r[7])));
}

// Prep (2048 threads): csum + codebook packed into MFMA A-frag order (split
// hi/lo bf16, 8 slots * 512 shorts = 8KB per tile). csum applied as f32 C-init
// in vq_main. Also zeroes hist/sse/done (kernel boundary publishes to vq_main).
__global__ void vq_prep(const float* __restrict__ cb, float* __restrict__ csum,
                        unsigned short* __restrict__ cbp,
                        unsigned int* __restrict__ hist,
                        double* __restrict__ sse,
                        unsigned int* __restrict__ done) {
    int g = blockIdx.x * 256 + threadIdx.x;   // 0..2047
    if (g < 1024) hist[g] = 0u;
    if (g == 1024) { *sse = 0.0; *done = 0u; }
    int t = g >> 6, lane = g & 63, l31 = lane & 31, half = lane >> 5;
    int row = t * 32 + l31;
    const float* r = cb + row * 64;
    float cs = np_pairwise_sumsq64(r);
    if (half == 0) csum[row] = cs;
    size_t tb = (size_t)t * 4096;             // shorts per tile (8 slots * 512)
    #pragma unroll
    for (int c = 0; c < 4; ++c) {
        bf16x8 h8, l8;
        #pragma unroll
        for (int j = 0; j < 8; ++j) {
            float f = r[c * 16 + half * 8 + j];
            unsigned short h = bf16rn(f);
            h8[j] = (short)h;
            l8[j] = (short)bf16rn(f - bf16tof(h));
        }
        *(bf16x8*)(cbp + tb + (size_t)(c * 2 + 0) * 512 + lane * 8) = h8;
        *(bf16x8*)(cbp + tb + (size_t)(c * 2 + 1) * 512 + lane * 8) = l8;
    }
}

// Main: R5-validated body (passed, absmax 3.8e-6, main 68.5us) + the fused
// fenceless finalize validated by R6/R7 (outputs 0/2 passed twice through it).
// Block = 128 points, 4 waves; per-block LDS staging of the packed codebook
// (global_load_lds 16B/lane, 2x4KB half-tile dbuf, one barrier per half-step:
// barrier's mandatory vmcnt(0)+lgkmcnt(0) drain IS the dbuf wait). Screen:
// split-bf16 (hi*hi + hi*lo + lo*hi), csum as exact-f32 C-init, med3 top-2.
// launch_bounds (256,1): measured gfx950 cap law arch-VGPR = 256/min_waves
// (min_waves>=4 capped to 64 VGPR and spilled 4x in R1/R2).
// NO __threadfence anywhere (R3: agent fence = buffer_wbl2 per block, ~120us).
__global__ __launch_bounds__(256, 1) void vq_main(
        const float* __restrict__ latents,
        const float* __restrict__ cb,
        const float* __restrict__ csum,
        const unsigned short* __restrict__ cbp,
        unsigned int* __restrict__ hist,
        double* __restrict__ sse,
        unsigned int* __restrict__ done,
        float* __restrict__ out) {
    __shared__ float xs[128 * 65];            // 33.3 KB, stride 65 (x, then q)
    __shared__ float tmax[32 * 128];          // 16 KB per-(tile,point) screen max
    __shared__ float csl[1024];               // 4 KB: -csum/2 (f32, exact)
    __shared__ __align__(16) short stg[2][2048];  // 8 KB: double-buffered half-tiles
    __shared__ float m1f[128];
    __shared__ int   fk[128], ambig[128], acount;
    __shared__ double wred[4];
    __shared__ int isLast;

    const int tid  = threadIdx.x;
    const int lane = tid & 63, wave = tid >> 6;   // wave 0..3
    const int n0 = blockIdx.x * 128;
    const int b = n0 >> 10, hw0 = n0 & 1023;
    const float* xg = latents + (size_t)b * C_DIM * HW + hw0;

    for (int i = tid; i < 128 * 64; i += 256) {
        int p = i & 127, d = i >> 7;
        xs[p * 65 + d] = xg[(size_t)d * HW + p];
    }
    for (int i = tid; i < 1024; i += 256) csl[i] = -0.5f * csum[i];
    if (tid == 0) acount = 0;
    __syncthreads();

    // B-frags: col = lane&31 -> point, k = (lane>>5)*8 + j
    const int l31 = lane & 31, half = lane >> 5;
    const int pb = (wave << 5) + l31;
    bf16x8 xh[4], xl[4];
    #pragma unroll
    for (int c = 0; c < 4; ++c)
        #pragma unroll
        for (int j = 0; j < 8; ++j) {
            float f = xs[pb * 65 + c * 16 + half * 8 + j];
            unsigned short h = bf16rn(f);
            xh[c][j] = (short)h;
            xl[c][j] = (short)bf16rn(f - bf16tof(h));
        }

    f32x16 zacc;
    #pragma unroll
    for (int r = 0; r < 16; ++r) zacc[r] = 0.0f;

    float m1 = -3e38f, m2 = -3e38f;
    int i1 = 0;
    const int RC[16] = {0,1,2,3,8,9,10,11,16,17,18,19,24,25,26,27};
    const int rh4 = half * 4;
    const char* cbpB = (const char*)cbp;      // step s covers bytes [s*4096, +4096)
    char* lds0 = (char*)&stg[0][0] + wave * 1024;
    char* lds1 = (char*)&stg[1][0] + wave * 1024;

    // prologue: stage step 0 (tile 0, half A) into buf0
    gload_lds16(cbpB + (size_t)tid * 16, lds0);

    for (int t = 0; t < 32; ++t) {
        // ---- step 2t (half A: chunks 0,1) ----
        __syncthreads();                      // drains buf0 load + prior ds_reads
        const bf16x8* s0 = (const bf16x8*)&stg[0][0];
        bf16x8 a0 = s0[lane], a1 = s0[64 + lane], a2 = s0[128 + lane], a3 = s0[192 + lane];
        f32x16 csv;
        {
            const int cb0 = (t << 5) + rh4;
            #pragma unroll
            for (int q = 0; q < 4; ++q) {
                float4 c4 = *(const float4*)&csl[cb0 + q * 8];
                csv[q * 4 + 0] = c4.x; csv[q * 4 + 1] = c4.y;
                csv[q * 4 + 2] = c4.z; csv[q * 4 + 3] = c4.w;
            }
        }
        // prefetch half B of tile t (drained at next barrier)
        gload_lds16(cbpB + ((size_t)(2 * t + 1)) * 4096 + (size_t)tid * 16, lds1);
        f32x16 acc0 = __builtin_amdgcn_mfma_f32_32x32x16_bf16(a0, xh[0], csv, 0, 0, 0);
        acc0 = __builtin_amdgcn_mfma_f32_32x32x16_bf16(a0, xl[0], acc0, 0, 0, 0);
        acc0 = __builtin_amdgcn_mfma_f32_32x32x16_bf16(a1, xh[0], acc0, 0, 0, 0);
        acc0 = __builtin_amdgcn_mfma_f32_32x32x16_bf16(a2, xh[1], acc0, 0, 0, 0);
        acc0 = __builtin_amdgcn_mfma_f32_32x32x16_bf16(a2, xl[1], acc0, 0, 0, 0);
        acc0 = __builtin_amdgcn_mfma_f32_32x32x16_bf16(a3, xh[1], acc0, 0, 0, 0);

        // ---- step 2t+1 (half B: chunks 2,3) ----
        __syncthreads();                      // drains buf1 load + buf0 ds_reads
        const bf16x8* s1 = (const bf16x8*)&stg[1][0];
        bf16x8 b0 = s1[lane], b1 = s1[64 + lane], b2 = s1[128 + lane], b3 = s1[192 + lane];
        if (t < 31)                           // prefetch half A of tile t+1
            gload_lds16(cbpB + ((size_t)(2 * t + 2)) * 4096 + (size_t)tid * 16, lds0);
        f32x16 acc1 = __builtin_amdgcn_mfma_f32_32x32x16_bf16(b0, xh[2], zacc, 0, 0, 0);
        acc1 = __builtin_amdgcn_mfma_f32_32x32x16_bf16(b0, xl[2], acc1, 0, 0, 0);
        acc1 = __builtin_amdgcn_mfma_f32_32x32x16_bf16(b1, xh[2], acc1, 0, 0, 0);
        acc1 = __builtin_amdgcn_mfma_f32_32x32x16_bf16(b2, xh[3], acc1, 0, 0, 0);
        acc1 = __builtin_amdgcn_mfma_f32_32x32x16_bf16(b2, xl[3], acc1, 0, 0, 0);
        acc1 = __builtin_amdgcn_mfma_f32_32x32x16_bf16(b3, xh[3], acc1, 0, 0, 0);

        // within-tile top-2 + first-argmax (5 VALU/value incl. the half-combine)
        float vl = -3e38f, sl = -3e38f;
        int kl = 0;
        #pragma unroll
        for (int r = 0; r < 16; ++r) {
            float v = acc0[r] + acc1[r];
            sl = __builtin_amdgcn_fmed3f(v, sl, vl);   // = max(sl, min(vl_old, v))
            bool c2 = v > vl;                           // strict >: first-max
            kl = c2 ? RC[r] : kl;
            vl = fmaxf(vl, v);
        }
        int k = (t << 5) + rh4 + kl;
        bool cg = vl > m1;                              // strict: earlier tile wins ties
        i1 = cg ? k : i1;
        float X = cg ? sl : m2;
        m2 = __builtin_amdgcn_fmed3f(vl, X, m1);        // = max(min(m1,vl), X)
        m1 = fmaxf(m1, vl);
        float tlm = fmaxf(vl, __shfl_xor(vl, 32, 64));
        if (half == 0) tmax[t * 128 + pb] = tlm;
    }

    // cross-half merge; ties resolve via ambiguous path
    {
        float m1o = __shfl_xor(m1, 32, 64);
        float m2o = __shfl_xor(m2, 32, 64);
        int   i1o = __shfl_xor(i1, 32, 64);
        m2 = fmaxf(fmaxf(m2, m2o), fminf(m1, m1o));
        i1 = (m1o > m1) ? i1o : i1;
        m1 = fmaxf(m1, m1o);
        if (half == 0) {
            m1f[pb] = m1;
            fk[pb] = i1;
            if (m2 >= m1 - EPS_A_W) {
                int a = atomicAdd(&acount, 1);
                ambig[a] = pb;
            }
        }
    }
    __syncthreads();

    // Exact rescan: one wave per ambiguous point, candidate tiles only.
    // Reference-bit-exact: dist = fl32(fl32(A+csum[k]) - fl32(2*seqFMA)).
    for (int a = wave; a < acount; a += 4) {
        int p = ambig[a];
        const float* xrow = &xs[p * 65];
        float Aq = np_pairwise_sumsq64(xrow);
        float thr = m1f[p] - EPS_T_W;
        unsigned long long best = ~0ULL;
        for (int t = 0; t < 32; ++t) {
            if (tmax[t * 128 + p] < thr) continue;   // wave-uniform branch
            if (lane < 32) {
                int k = (t << 5) + lane;
                const float* crow = cb + (size_t)k * 64;
                float m = 0.0f;
                #pragma unroll
                for (int d = 0; d < 64; ++d) m = __fmaf_rn(xrow[d], crow[d], m);
                float D = __fsub_rn(__fadd_rn(Aq, csum[k]), __fmul_rn(2.0f, m));
                unsigned long long key =
                    ((unsigned long long)__float_as_uint(D) << 10) | (unsigned)k;
                best = (key < best) ? key : best;
            }
        }
        #pragma unroll
        for (int off = 32; off > 0; off >>= 1) {
            unsigned long long o = __shfl_xor(best, off, 64);
            best = (o < best) ? o : best;
        }
        if (lane == 0) fk[p] = (int)(best & 1023ULL);
    }
    __syncthreads();

    // indices + histogram
    if (tid < 128) {
        int myk = fk[tid];
        out[OUT_I_OFF + n0 + tid] = (float)myk;
        atomicAdd(&hist[myk], 1u);
    }
    // Fused stage+SSE: read each selected cb row ONCE row-coalesced (float4),
    // accumulate f64 SSE against x in xs, overwrite xs with q for write-out.
    double e = 0.0;
    #pragma unroll
    for (int i2 = 0; i2 < 8; ++i2) {
        int i = tid + i2 * 256;               // 0..2047
        int p = i >> 4, seg = i & 15;
        const float4 q = *(const float4*)(cb + (size_t)fk[p] * 64 + seg * 4);
        float* xp = &xs[p * 65 + seg * 4];    // stride-65: only 4B aligned -> scalar ops
        float x0 = xp[0], x1 = xp[1], x2 = xp[2], x3 = xp[3];
        double d0 = (double)x0 - (double)q.x; e = fma(d0, d0, e);
        double d1 = (double)x1 - (double)q.y; e = fma(d1, d1, e);
        double d2 = (double)x2 - (double)q.z; e = fma(d2, d2, e);
        double d3 = (double)x3 - (double)q.w; e = fma(d3, d3, e);
        xp[0] = q.x; xp[1] = q.y; xp[2] = q.z; xp[3] = q.w;
    }
    #pragma unroll
    for (int off = 32; off > 0; off >>= 1) e += __shfl_down(e, off, 64);
    if (lane == 0) wred[wave] = e;
    __syncthreads();
    if (tid == 0) {
        double s = 0.0;
        #pragma unroll
        for (int w = 0; w < 4; ++w) s += wred[w];
        atomicAdd(sse, s);
    }
    // quantized [B,C,H,W]: coalesced 128-float store rows per c, from staged xs
    for (int i = tid; i < 128 * 64; i += 256) {
        int p = i & 127, c = i >> 7;
        out[OUT_Q_OFF + (size_t)b * 65536 + (size_t)c * HW + hw0 + p] = xs[p * 65 + c];
    }

    // Fenceless fused finalize (validated: R6/R7 outputs 0/2 passed through
    // this path twice). Barrier's mandatory vmcnt(0) drain means every
    // thread's hist/sse device atomics completed before tid0 bumps the done
    // counter; last block reads via agent-scope atomic loads. No buffer_wbl2.
    __syncthreads();
    if (tid == 0)
        isLast = (atomicAdd(done, 1u) == (unsigned)(gridDim.x - 1)) ? 1 : 0;
    __syncthreads();
    if (isLast) {
        double s = 0.0;
        for (int i = tid; i < K_CODES; i += 256) {
            unsigned int h = __hip_atomic_load(&hist[i], __ATOMIC_RELAXED,
                                               __HIP_MEMORY_SCOPE_AGENT);
            double pr = (double)h / (double)N_PTS;
            s += pr * log(pr + 1e-10);
        }
        #pragma unroll
        for (int off = 32; off > 0; off >>= 1) s += __shfl_down(s, off, 64);
        if (lane == 0) wred[wave] = s;
        __syncthreads();
        if (tid == 0) {
            double st = 0.0;
            #pragma unroll
            for (int w = 0; w < 4; ++w) st += wred[w];
            double sv = __hip_atomic_load(sse, __ATOMIC_RELAXED,
                                          __HIP_MEMORY_SCOPE_AGENT);
            out[OUT_P_OFF] = (float)exp(-st);
            out[0] = (float)(1.25 * sv / (double)Q_ELEMS);
        }
    }
}

extern "C" void kernel_launch(void* const* d_in, const int* in_sizes, int n_in,
                              void* d_out, int out_size, void* d_ws, size_t ws_size,
                              hipStream_t stream) {
    const float* latents = (const float*)d_in[0];
    const float* cb      = (const float*)d_in[1];
    float* out = (float*)d_out;
    char* ws = (char*)d_ws;

    unsigned int*   hist = (unsigned int*)(ws + WS_HIST);
    double*         sse  = (double*)(ws + WS_SSE);
    unsigned int*   done = (unsigned int*)(ws + WS_DONE);
    float*          csum = (float*)(ws + WS_CSUM);
    unsigned short* cbp  = (unsigned short*)(ws + WS_CBP);

    vq_prep<<<8, 256, 0, stream>>>(cb, csum, cbp, hist, sse, done);
    vq_main<<<N_PTS / 128, 256, 0, stream>>>(latents, cb, csum, cbp,
                                             hist, sse, done, out);
}

// Round 10
// 127.042 us; speedup vs baseline: 1.0769x; 1.0532x over previous
//
#include <hip/hip_runtime.h>

// Problem constants
#define N_PTS   65536      // B*H*W = 64*32*32
#define K_CODES 1024
#define C_DIM   64
#define HW      1024
#define Q_ELEMS 4194304

// d_out layout (float32): [vq_loss(1) | quantized(4194304) | perplexity(1) | indices(65536)]
#define OUT_Q_OFF 1
#define OUT_P_OFF 4194305
#define OUT_I_OFF 4194306

// ws layout (bytes)
#define WS_HIST 0          // 1024 u32    (4096)
#define WS_SSE  4096       // 1 double    (8)
#define WS_DONE 4104       // 1 u32       (4)
#define WS_CSUM 8192       // 1024 f32    (4096)
#define WS_CBP  16384      // packed A-frags: 32 tiles * 8 slots * 512 shorts = 262144 B

// Screen metric is w = x.c - csum/2 (argmin dist == argmax w). Proven dist-space
// thresholds EPS_A=1.5e-4 / EPS_T=4e-4 map to w-space /2.
#define EPS_A_W 7.5e-5f    // ambiguous if m2 >= m1 - EPS_A_W
#define EPS_T_W 2.0e-4f    // candidate tile if tmax >= m1 - EPS_T_W

typedef float f32x16 __attribute__((ext_vector_type(16)));
typedef short bf16x8 __attribute__((ext_vector_type(8)));

__device__ __forceinline__ unsigned short bf16rn(float f) {
    unsigned int u = __float_as_uint(f);
    return (unsigned short)((u + 0x7FFFu + ((u >> 16) & 1u)) >> 16);
}
__device__ __forceinline__ float bf16tof(unsigned short h) {
    return __uint_as_float(((unsigned int)h) << 16);
}

// async global->LDS, 16B per lane, wave-uniform LDS base (lane*16 added by HW)
__device__ __forceinline__ void gload_lds16(const void* g, void* l) {
    __builtin_amdgcn_global_load_lds(
        (const __attribute__((address_space(1))) unsigned int*)g,
        (__attribute__((address_space(3))) unsigned int*)l, 16, 0, 0);
}

// numpy pairwise sum (n=64): 8 accumulators striding 8, then pairwise combine.
__device__ __forceinline__ float np_pairwise_sumsq64(const float* a) {
    float r[8];
    #pragma unroll
    for (int j = 0; j < 8; ++j) r[j] = __fmul_rn(a[j], a[j]);
    #pragma unroll
    for (int i = 8; i < 64; i += 8) {
        #pragma unroll
        for (int j = 0; j < 8; ++j)
            r[j] = __fadd_rn(r[j], __fmul_rn(a[i + j], a[i + j]));
    }
    return __fadd_rn(__fadd_rn(__fadd_rn(r[0], r[1]), __fadd_rn(r[2], r[3])),
                     __fadd_rn(__fadd_rn(r[4], r[5]), __fadd_rn(r[6], r[7])));
}

// Prep (2048 threads): csum + codebook packed into MFMA A-frag order (split
// hi/lo bf16, slots [hi0,lo0,hi1,lo1,hi2,lo2,hi3,lo3] * 512 shorts = 8KB/tile).
// Also zeroes hist/sse/done (kernel boundary publishes to vq_main).
// BYTE-IDENTICAL to R9 (validated).
__global__ void vq_prep(const float* __restrict__ cb, float* __restrict__ csum,
                        unsigned short* __restrict__ cbp,
                        unsigned int* __restrict__ hist,
                        double* __restrict__ sse,
                        unsigned int* __restrict__ done) {
    int g = blockIdx.x * 256 + threadIdx.x;   // 0..2047
    if (g < 1024) hist[g] = 0u;
    if (g == 1024) { *sse = 0.0; *done = 0u; }
    int t = g >> 6, lane = g & 63, l31 = lane & 31, half = lane >> 5;
    int row = t * 32 + l31;
    const float* r = cb + row * 64;
    float cs = np_pairwise_sumsq64(r);
    if (half == 0) csum[row] = cs;
    size_t tb = (size_t)t * 4096;             // shorts per tile (8 slots * 512)
    #pragma unroll
    for (int c = 0; c < 4; ++c) {
        bf16x8 h8, l8;
        #pragma unroll
        for (int j = 0; j < 8; ++j) {
            float f = r[c * 16 + half * 8 + j];
            unsigned short h = bf16rn(f);
            h8[j] = (short)h;
            l8[j] = (short)bf16rn(f - bf16tof(h));
        }
        *(bf16x8*)(cbp + tb + (size_t)(c * 2 + 0) * 512 + lane * 8) = h8;
        *(bf16x8*)(cbp + tb + (size_t)(c * 2 + 1) * 512 + lane * 8) = l8;
    }
}

// Main: R9 body with ONE structural change: one full 8KB tile per phase
// (2x8KB LDS dbuf) -> 33 barriers instead of 65. R9 cycle accounting: 59% of
// cycles issue nothing; the 64 per-tile vmcnt(0)+lgkmcnt(0) barrier drains are
// the prime unmodeled cost. Full-tile phases also put both 6-MFMA chains
// (acc0, acc1) in one phase (2 independent dep chains on the MFMA pipe) and
// give the t+1 prefetch a full phase to cover L2 latency. To fit 64KB LDS,
// tmax is stored bf16 (RN); the rescan tile-include test compensates
// conservatively (tm + |tm|*2^-8 >= thr: upper-bounds true tlm, so tiles are
// only ever ADDED, never dropped -> EPS_T guarantee intact). Screen product
// order identical to R9 -> identical values -> proven EPS bands valid.
// launch_bounds (256,1): measured gfx950 cap law arch-VGPR = 256/min_waves.
// NO __threadfence (R3: agent fence = buffer_wbl2 per block, ~120us).
__global__ __launch_bounds__(256, 1) void vq_main(
        const float* __restrict__ latents,
        const float* __restrict__ cb,
        const float* __restrict__ csum,
        const unsigned short* __restrict__ cbp,
        unsigned int* __restrict__ hist,
        double* __restrict__ sse,
        unsigned int* __restrict__ done,
        float* __restrict__ out) {
    __shared__ float xs[128 * 65];            // 33.3 KB, stride 65 (x, then q)
    __shared__ unsigned short tmaxh[32 * 128];// 8 KB per-(tile,point) max, bf16
    __shared__ float csl[1024];               // 4 KB: -csum/2 (f32, exact)
    __shared__ __align__(16) short stg[2][4096];  // 16 KB: double-buffered 8KB tiles
    __shared__ float m1f[128];
    __shared__ int   fk[128], ambig[128], acount;
    __shared__ double wred[4];
    __shared__ int isLast;

    const int tid  = threadIdx.x;
    const int lane = tid & 63, wave = tid >> 6;   // wave 0..3
    const int n0 = blockIdx.x * 128;
    const int b = n0 >> 10, hw0 = n0 & 1023;
    const float* xg = latents + (size_t)b * C_DIM * HW + hw0;

    for (int i = tid; i < 128 * 64; i += 256) {
        int p = i & 127, d = i >> 7;
        xs[p * 65 + d] = xg[(size_t)d * HW + p];
    }
    for (int i = tid; i < 1024; i += 256) csl[i] = -0.5f * csum[i];
    if (tid == 0) acount = 0;
    __syncthreads();

    // B-frags: col = lane&31 -> point, k = (lane>>5)*8 + j
    const int l31 = lane & 31, half = lane >> 5;
    const int pb = (wave << 5) + l31;
    bf16x8 xh[4], xl[4];
    #pragma unroll
    for (int c = 0; c < 4; ++c)
        #pragma unroll
        for (int j = 0; j < 8; ++j) {
            float f = xs[pb * 65 + c * 16 + half * 8 + j];
            unsigned short h = bf16rn(f);
            xh[c][j] = (short)h;
            xl[c][j] = (short)bf16rn(f - bf16tof(h));
        }

    f32x16 zacc;
    #pragma unroll
    for (int r = 0; r < 16; ++r) zacc[r] = 0.0f;

    float m1 = -3e38f, m2 = -3e38f;
    int i1 = 0;
    const int RC[16] = {0,1,2,3,8,9,10,11,16,17,18,19,24,25,26,27};
    const int rh4 = half * 4;
    const char* cbpB = (const char*)cbp;      // tile t = bytes [t*8192, +8192)
    // staging dests: per wave, call k covers buf + k*4096 + wave*1024 (+lane*16)
    char* buf0 = (char*)&stg[0][0] + wave * 1024;
    char* buf1 = (char*)&stg[1][0] + wave * 1024;

    // prologue: stage tile 0 into buf0 (2 x 4KB)
    gload_lds16(cbpB + (size_t)tid * 16, buf0);
    gload_lds16(cbpB + 4096 + (size_t)tid * 16, buf0 + 4096);

    for (int t = 0; t < 32; ++t) {
        __syncthreads();   // drains tile-t gload (vmcnt) + tile-(t-1) ds_reads (lgkm)
        char* nxt = (t & 1) ? buf0 : buf1;
        if (t + 1 < 32) {  // prefetch t+1 into the buffer freed at this barrier
            const char* src = cbpB + ((size_t)(t + 1)) * 8192 + (size_t)tid * 16;
            gload_lds16(src, nxt);
            gload_lds16(src + 4096, nxt + 4096);
        }
        const bf16x8* s = (const bf16x8*)((t & 1) ? &stg[1][0] : &stg[0][0]);
        // slots: [hi0,lo0,hi1,lo1,hi2,lo2,hi3,lo3], 64 frags (bf16x8) each
        bf16x8 h0 = s[0 * 64 + lane], o0 = s[1 * 64 + lane];
        bf16x8 h1 = s[2 * 64 + lane], o1 = s[3 * 64 + lane];
        bf16x8 h2 = s[4 * 64 + lane], o2 = s[5 * 64 + lane];
        bf16x8 h3 = s[6 * 64 + lane], o3 = s[7 * 64 + lane];
        f32x16 csv;
        {
            const int cb0 = (t << 5) + rh4;
            #pragma unroll
            for (int q = 0; q < 4; ++q) {
                float4 c4 = *(const float4*)&csl[cb0 + q * 8];
                csv[q * 4 + 0] = c4.x; csv[q * 4 + 1] = c4.y;
                csv[q * 4 + 2] = c4.z; csv[q * 4 + 3] = c4.w;
            }
        }
        // two independent 6-MFMA chains (identical product set/order to R9)
        f32x16 acc0 = __builtin_amdgcn_mfma_f32_32x32x16_bf16(h0, xh[0], csv, 0, 0, 0);
        f32x16 acc1 = __builtin_amdgcn_mfma_f32_32x32x16_bf16(h2, xh[2], zacc, 0, 0, 0);
        acc0 = __builtin_amdgcn_mfma_f32_32x32x16_bf16(h0, xl[0], acc0, 0, 0, 0);
        acc1 = __builtin_amdgcn_mfma_f32_32x32x16_bf16(h2, xl[2], acc1, 0, 0, 0);
        acc0 = __builtin_amdgcn_mfma_f32_32x32x16_bf16(o0, xh[0], acc0, 0, 0, 0);
        acc1 = __builtin_amdgcn_mfma_f32_32x32x16_bf16(o2, xh[2], acc1, 0, 0, 0);
        acc0 = __builtin_amdgcn_mfma_f32_32x32x16_bf16(h1, xh[1], acc0, 0, 0, 0);
        acc1 = __builtin_amdgcn_mfma_f32_32x32x16_bf16(h3, xh[3], acc1, 0, 0, 0);
        acc0 = __builtin_amdgcn_mfma_f32_32x32x16_bf16(h1, xl[1], acc0, 0, 0, 0);
        acc1 = __builtin_amdgcn_mfma_f32_32x32x16_bf16(h3, xl[3], acc1, 0, 0, 0);
        acc0 = __builtin_amdgcn_mfma_f32_32x32x16_bf16(o1, xh[1], acc0, 0, 0, 0);
        acc1 = __builtin_amdgcn_mfma_f32_32x32x16_bf16(o3, xh[3], acc1, 0, 0, 0);

        // within-tile top-2 + first-argmax (med3, cmp, cnd, fmax per value)
        float vl = -3e38f, sl = -3e38f;
        int kl = 0;
        #pragma unroll
        for (int r = 0; r < 16; ++r) {
            float v = acc0[r] + acc1[r];
            sl = __builtin_amdgcn_fmed3f(v, sl, vl);   // = max(sl, min(vl_old, v))
            bool c2 = v > vl;                           // strict >: first-max
            kl = c2 ? RC[r] : kl;
            vl = fmaxf(vl, v);
        }
        int k = (t << 5) + rh4 + kl;
        bool cg = vl > m1;                              // strict: earlier tile wins ties
        i1 = cg ? k : i1;
        float X = cg ? sl : m2;
        m2 = __builtin_amdgcn_fmed3f(vl, X, m1);        // = max(min(m1,vl), X)
        m1 = fmaxf(m1, vl);
        float tlm = fmaxf(vl, __shfl_xor(vl, 32, 64));
        if (half == 0) tmaxh[t * 128 + pb] = bf16rn(tlm);
    }

    // cross-half merge; ties resolve via ambiguous path
    {
        float m1o = __shfl_xor(m1, 32, 64);
        float m2o = __shfl_xor(m2, 32, 64);
        int   i1o = __shfl_xor(i1, 32, 64);
        m2 = fmaxf(fmaxf(m2, m2o), fminf(m1, m1o));
        i1 = (m1o > m1) ? i1o : i1;
        m1 = fmaxf(m1, m1o);
        if (half == 0) {
            m1f[pb] = m1;
            fk[pb] = i1;
            if (m2 >= m1 - EPS_A_W) {
                int a = atomicAdd(&acount, 1);
                ambig[a] = pb;
            }
        }
    }
    __syncthreads();

    // Exact rescan: one wave per ambiguous point, candidate tiles only.
    // tmax is bf16(RN): true tlm <= tm + |tm|*2^-8, so the include test uses
    // that upper bound -> only ever adds tiles vs f32 tmax (EPS_T safe).
    // Reference-bit-exact: dist = fl32(fl32(A+csum[k]) - fl32(2*seqFMA)).
    for (int a = wave; a < acount; a += 4) {
        int p = ambig[a];
        const float* xrow = &xs[p * 65];
        float Aq = np_pairwise_sumsq64(xrow);
        float thr = m1f[p] - EPS_T_W;
        unsigned long long best = ~0ULL;
        for (int t = 0; t < 32; ++t) {
            float tm = bf16tof(tmaxh[t * 128 + p]);     // wave-uniform branch
            if (__fmaf_rn(fabsf(tm), 0x1p-8f, tm) < thr) continue;
            if (lane < 32) {
                int k = (t << 5) + lane;
                const float* crow = cb + (size_t)k * 64;
                float m = 0.0f;
                #pragma unroll
                for (int d = 0; d < 64; ++d) m = __fmaf_rn(xrow[d], crow[d], m);
                float D = __fsub_rn(__fadd_rn(Aq, csum[k]), __fmul_rn(2.0f, m));
                unsigned long long key =
                    ((unsigned long long)__float_as_uint(D) << 10) | (unsigned)k;
                best = (key < best) ? key : best;
            }
        }
        #pragma unroll
        for (int off = 32; off > 0; off >>= 1) {
            unsigned long long o = __shfl_xor(best, off, 64);
            best = (o < best) ? o : best;
        }
        if (lane == 0) fk[p] = (int)(best & 1023ULL);
    }
    __syncthreads();

    // indices + histogram
    if (tid < 128) {
        int myk = fk[tid];
        out[OUT_I_OFF + n0 + tid] = (float)myk;
        atomicAdd(&hist[myk], 1u);
    }
    // Fused stage+SSE: read each selected cb row ONCE row-coalesced (float4),
    // accumulate f64 SSE against x in xs, overwrite xs with q for write-out.
    double e = 0.0;
    #pragma unroll
    for (int i2 = 0; i2 < 8; ++i2) {
        int i = tid + i2 * 256;               // 0..2047
        int p = i >> 4, seg = i & 15;
        const float4 q = *(const float4*)(cb + (size_t)fk[p] * 64 + seg * 4);
        float* xp = &xs[p * 65 + seg * 4];    // stride-65: only 4B aligned -> scalar ops
        float x0 = xp[0], x1 = xp[1], x2 = xp[2], x3 = xp[3];
        double d0 = (double)x0 - (double)q.x; e = fma(d0, d0, e);
        double d1 = (double)x1 - (double)q.y; e = fma(d1, d1, e);
        double d2 = (double)x2 - (double)q.z; e = fma(d2, d2, e);
        double d3 = (double)x3 - (double)q.w; e = fma(d3, d3, e);
        xp[0] = q.x; xp[1] = q.y; xp[2] = q.z; xp[3] = q.w;
    }
    #pragma unroll
    for (int off = 32; off > 0; off >>= 1) e += __shfl_down(e, off, 64);
    if (lane == 0) wred[wave] = e;
    __syncthreads();
    if (tid == 0) {
        double s = 0.0;
        #pragma unroll
        for (int w = 0; w < 4; ++w) s += wred[w];
        atomicAdd(sse, s);
    }
    // quantized [B,C,H,W]: coalesced 128-float store rows per c, from staged xs
    for (int i = tid; i < 128 * 64; i += 256) {
        int p = i & 127, c = i >> 7;
        out[OUT_Q_OFF + (size_t)b * 65536 + (size_t)c * HW + hw0 + p] = xs[p * 65 + c];
    }

    // Fenceless fused finalize (validated R6/R7/R9). Barrier's mandatory
    // vmcnt(0) drain means every thread's hist/sse device atomics completed
    // before tid0 bumps the done counter; last block reads via agent-scope
    // atomic loads. No buffer_wbl2 anywhere.
    __syncthreads();
    if (tid == 0)
        isLast = (atomicAdd(done, 1u) == (unsigned)(gridDim.x - 1)) ? 1 : 0;
    __syncthreads();
    if (isLast) {
        double s = 0.0;
        for (int i = tid; i < K_CODES; i += 256) {
            unsigned int h = __hip_atomic_load(&hist[i], __ATOMIC_RELAXED,
                                               __HIP_MEMORY_SCOPE_AGENT);
            double pr = (double)h / (double)N_PTS;
            s += pr * log(pr + 1e-10);
        }
        #pragma unroll
        for (int off = 32; off > 0; off >>= 1) s += __shfl_down(s, off, 64);
        if (lane == 0) wred[wave] = s;
        __syncthreads();
        if (tid == 0) {
            double st = 0.0;
            #pragma unroll
            for (int w = 0; w < 4; ++w) st += wred[w];
            double sv = __hip_atomic_load(sse, __ATOMIC_RELAXED,
                                          __HIP_MEMORY_SCOPE_AGENT);
            out[OUT_P_OFF] = (float)exp(-st);
            out[0] = (float)(1.25 * sv / (double)Q_ELEMS);
        }
    }
}

extern "C" void kernel_launch(void* const* d_in, const int* in_sizes, int n_in,
                              void* d_out, int out_size, void* d_ws, size_t ws_size,
                              hipStream_t stream) {
    const float* latents = (const float*)d_in[0];
    const float* cb      = (const float*)d_in[1];
    float* out = (float*)d_out;
    char* ws = (char*)d_ws;

    unsigned int*   hist = (unsigned int*)(ws + WS_HIST);
    double*         sse  = (double*)(ws + WS_SSE);
    unsigned int*   done = (unsigned int*)(ws + WS_DONE);
    float*          csum = (float*)(ws + WS_CSUM);
    unsigned short* cbp  = (unsigned short*)(ws + WS_CBP);

    vq_prep<<<8, 256, 0, stream>>>(cb, csum, cbp, hist, sse, done);
    vq_main<<<N_PTS / 128, 256, 0, stream>>>(latents, cb, csum, cbp,
                                             hist, sse, done, out);
}